// Round 11
// baseline (26.842 us; speedup 1.0000x reference)
//
#include <hip/hip_runtime.h>
#include <math.h>

#define NSZ 512
#define MSZ 256
#define NPIX (6 * NSZ * NSZ)                      // 1,572,864 vertices
#define NQu  261121u                              // (NSZ-1)^2 quads per face
#define NQ2u 522242u                              // 2*NQu tris per face
#define NFACE 3133452                             // 6*2*NQu
#define F3TOT 9400356                             // NFACE*3 floats
#define NFT12 783363                              // F3TOT/12 (4 whole tris / thread)
#define TS 32                                     // output tile
#define HS 34                                     // vert halo
#define QS 33                                     // quad halo
#define NVB 1536                                  // 6*16*16 vert blocks
#define NFB ((NFT12 + 255) / 256)                 // 3061 faces blocks
#define GRID (NVB + NFB)

typedef __fp16 h2_t __attribute__((ext_vector_type(2)));

// ---- fast math helpers (raw HW op + 1 Newton step) -----------------------
__device__ inline float fast_rcp(float x) {
    float r = __builtin_amdgcn_rcpf(x);
    return r * (2.0f - x * r);
}
__device__ inline float fast_rsqrt(float d) {
    float r = __builtin_amdgcn_rsqf(d);
    return r * (1.5f - 0.5f * d * r * r);
}
__device__ inline float fast_sigmoid(float x) {
    float e = __builtin_amdgcn_exp2f(-1.442695040888963f * x);
    return fast_rcp(1.0f + e);
}
__device__ inline float lerpf(float a, float b, float w) {
    return __builtin_fmaf(w, b - a, a);
}
// pack two floats to half2 bits (one v_cvt_pkrtz_f16_f32)
__device__ inline unsigned pkh2(float x, float y) {
    h2_t h = __builtin_amdgcn_cvt_pkrtz(x, y);
    return __builtin_bit_cast(unsigned, h);
}
__device__ inline float2 uph2(unsigned u) {
    h2_t h = __builtin_bit_cast(h2_t, u);
    return make_float2((float)h.x, (float)h.y);
}
__device__ inline float uph_lo(unsigned u) {
    h2_t h = __builtin_bit_cast(h2_t, u);
    return (float)h.x;
}

__global__ __launch_bounds__(256, 8) void k_all(const float* __restrict__ vrt,
                                                const float* __restrict__ nrm,
                                                const float* __restrict__ ps,
                                                float* __restrict__ out0,
                                                float* __restrict__ out1,
                                                float* __restrict__ out2) {
    // LDS total: 4624 + 2312 (pad to 2316) + 3*4356 = 20,008 B -> 8 blocks/CU
    __shared__ unsigned svXY[HS * HS];        // vert (x,y) fp16-packed
    __shared__ unsigned short svZ[HS * HS];   // vert z fp16 bits
    __shared__ unsigned tnXY0[QS * QS];       // tri0 normal (x,y)
    __shared__ unsigned tnXY1[QS * QS];       // tri1 normal (x,y)
    __shared__ unsigned tnZZ [QS * QS];       // (z0, z1) packed

    int blk = blockIdx.x;

    if (blk >= NVB) {
        // ========== faces path: 12 floats = 4 whole tris / thread ==========
        int t = (blk - NVB) * 256 + threadIdx.x;
        if (t >= NFT12) return;
        unsigned tri = 4u * (unsigned)t;          // j = 12t -> tri = 4t
        unsigned s   = tri / NQ2u;
        unsigned r1  = tri - s * NQ2u;
        unsigned ty  = (r1 >= NQu) ? 1u : 0u;
        unsigned qi  = r1 - ty * NQu;
        unsigned R   = qi / 511u;
        unsigned Q   = qi - R * 511u;

        unsigned a[4], tt[4];
        unsigned aq = Q, aR = R, aty = ty, as_ = s;
#pragma unroll
        for (int k = 0; k < 4; ++k) {
            a[k]  = (as_ << 18) + (aR << 9) + aq;
            tt[k] = aty;
            aq++;
            if (aq == 511u) {
                aq = 0u; aR++;
                if (aR == 511u) { aR = 0u; aty ^= 1u; if (aty == 0u) as_++; }
            }
        }
        float w[12];
#pragma unroll
        for (int k = 0; k < 4; ++k) {
            w[3*k + 0] = (float)(a[k] + (tt[k] ? 1u : 0u));
            w[3*k + 1] = (float)(a[k] + (tt[k] ? 513u : 1u));
            w[3*k + 2] = (float)(a[k] + 512u);
        }
        float4* o = (float4*)out1 + 3 * t;
        o[0] = make_float4(w[0], w[1], w[2],  w[3]);
        o[1] = make_float4(w[4], w[5], w[6],  w[7]);
        o[2] = make_float4(w[8], w[9], w[10], w[11]);
        return;
    }

    // ========== vert + normals path ==========
    int f   = blk >> 8;
    int tl  = blk & 255;
    int tr  = (tl >> 4) * TS;
    int tq  = (tl & 15) * TS;
    int fbm = f * (MSZ * MSZ);
    int fbn = f * (NSZ * NSZ);

    // phase 1: 34x34 halo of displaced verts -> sv (fp16) + interior -> out0 (fp32)
    const float scale = 255.0f / 511.0f;
    for (int p = threadIdx.x; p < HS * HS; p += 256) {
        int pr = p / HS, pq = p - pr * HS;
        int y = tr + pr - 1, x = tq + pq - 1;
        int yc = min(max(y, 0), NSZ - 1);
        int xc = min(max(x, 0), NSZ - 1);

        float cy = (float)yc * scale;
        float cx = (float)xc * scale;
        int iy0 = min((int)cy, MSZ - 1);
        int ix0 = min((int)cx, MSZ - 1);
        float wy = cy - (float)iy0;
        float wx = cx - (float)ix0;
        int   iya = min(iy0, MSZ - 2);
        int   ixa = min(ix0, MSZ - 2);
        float wya = (iy0 < MSZ - 1) ? wy : 1.0f;
        float wxa = (ix0 < MSZ - 1) ? wx : 1.0f;

        int g0 = (fbm + iya * MSZ + ixa) * 3;     // row iya: 6 contiguous floats
        int g1 = g0 + MSZ * 3;                     // row iya+1

        // vrt first (consume before nrm loads -> lower register pressure)
        float vx, vy, vz;
        {
            float a0 = vrt[g0], a1 = vrt[g0+1], a2 = vrt[g0+2];
            float a3 = vrt[g0+3], a4 = vrt[g0+4], a5 = vrt[g0+5];
            float b0 = vrt[g1], b1 = vrt[g1+1], b2 = vrt[g1+2];
            float b3 = vrt[g1+3], b4 = vrt[g1+4], b5 = vrt[g1+5];
            vx = lerpf(lerpf(a0, a3, wxa), lerpf(b0, b3, wxa), wya);
            vy = lerpf(lerpf(a1, a4, wxa), lerpf(b1, b4, wxa), wya);
            vz = lerpf(lerpf(a2, a5, wxa), lerpf(b2, b5, wxa), wya);
        }
        float nx, ny, nz;
        {
            float a0 = nrm[g0], a1 = nrm[g0+1], a2 = nrm[g0+2];
            float a3 = nrm[g0+3], a4 = nrm[g0+4], a5 = nrm[g0+5];
            float b0 = nrm[g1], b1 = nrm[g1+1], b2 = nrm[g1+2];
            float b3 = nrm[g1+3], b4 = nrm[g1+4], b5 = nrm[g1+5];
            nx = lerpf(lerpf(a0, a3, wxa), lerpf(b0, b3, wxa), wya);
            ny = lerpf(lerpf(a1, a4, wxa), lerpf(b1, b4, wxa), wya);
            nz = lerpf(lerpf(a2, a5, wxa), lerpf(b2, b5, wxa), wya);
        }

        float mag = __builtin_amdgcn_sqrtf(nx * nx + ny * ny + nz * nz);
        float sig = fast_sigmoid(ps[fbn + yc * NSZ + xc]);
        float add = 0.5f * sig * mag;
        float ox = vx + add, oy = vy + add, oz = vz + add;

        svXY[p] = pkh2(ox, oy);
        svZ[p]  = (unsigned short)(pkh2(oz, 0.0f) & 0xffffu);
        if (pr >= 1 && pr <= TS && pq >= 1 && pq <= TS) {
            int gi = (fbn + y * NSZ + x) * 3;
            out0[gi + 0] = ox;
            out0[gi + 1] = oy;
            out0[gi + 2] = oz;
        }
    }
    __syncthreads();

    // phase 1.5: unit normals of 33x33 quads' 2 tris, ONCE (fp16 verts in,
    // fp32 cross, fp16-packed out). Clamped-halo duplicate rows are fp16-
    // identical -> out-of-face tris give exactly-zero cross -> contribute 0.
    for (int p = threadIdx.x; p < QS * QS; p += 256) {
        int Ri = p / QS, Qi = p - Ri * QS;
        int iA = Ri * HS + Qi;
        int iB = iA + 1;
        int iC = iA + HS;
        int iD = iC + 1;

        float2 Axy = uph2(svXY[iA]); float Az = uph_lo((unsigned)svZ[iA]);
        float2 Bxy = uph2(svXY[iB]); float Bz = uph_lo((unsigned)svZ[iB]);
        float2 Cxy = uph2(svXY[iC]); float Cz = uph_lo((unsigned)svZ[iC]);
        float2 Dxy = uph2(svXY[iD]); float Dz = uph_lo((unsigned)svZ[iD]);

        float n0x, n0y, n0z;
        {   // tri0: (A, B, C)
            float e1x = Bxy.x - Axy.x, e1y = Bxy.y - Axy.y, e1z = Bz - Az;
            float e2x = Cxy.x - Axy.x, e2y = Cxy.y - Axy.y, e2z = Cz - Az;
            float cx = e1y * e2z - e1z * e2y;
            float cy = e1z * e2x - e1x * e2z;
            float cz = e1x * e2y - e1y * e2x;
            float d  = fmaxf(cx * cx + cy * cy + cz * cz, 1e-24f);
            float r  = fast_rsqrt(d);
            n0x = cx * r; n0y = cy * r; n0z = cz * r;
        }
        float n1x, n1y, n1z;
        {   // tri1: (B, D, C)
            float e1x = Dxy.x - Bxy.x, e1y = Dxy.y - Bxy.y, e1z = Dz - Bz;
            float e2x = Cxy.x - Bxy.x, e2y = Cxy.y - Bxy.y, e2z = Cz - Bz;
            float cx = e1y * e2z - e1z * e2y;
            float cy = e1z * e2x - e1x * e2z;
            float cz = e1x * e2y - e1y * e2x;
            float d  = fmaxf(cx * cx + cy * cy + cz * cz, 1e-24f);
            float r  = fast_rsqrt(d);
            n1x = cx * r; n1y = cy * r; n1z = cz * r;
        }
        tnXY0[p] = pkh2(n0x, n0y);
        tnXY1[p] = pkh2(n1x, n1y);
        tnZZ [p] = pkh2(n0z, n1z);
    }
    __syncthreads();

    // phase 2: vertex normal = normalize( sum of 6 adjacent tri normals )
    float sg = (f == 1 || f == 2 || f == 5) ? 1.0f : -1.0f;
    for (int p = threadIdx.x; p < TS * TS; p += 256) {
        int r = p >> 5, q = p & 31;
        int q00 = r * QS + q;
        int q01 = q00 + 1;
        int q10 = q00 + QS;
        int q11 = q10 + 1;

        // tri0 contributions: quads q11, q10, q01 ; tri1: q10, q00, q01
        float2 a0 = uph2(tnXY0[q11]);
        float2 a1 = uph2(tnXY0[q10]);
        float2 a2 = uph2(tnXY0[q01]);
        float2 b0 = uph2(tnXY1[q10]);
        float2 b1 = uph2(tnXY1[q00]);
        float2 b2 = uph2(tnXY1[q01]);
        float2 zA = uph2(tnZZ[q11]);   // (z0@q11, z1@q11)
        float2 zB = uph2(tnZZ[q10]);
        float2 zC = uph2(tnZZ[q01]);
        float2 zD = uph2(tnZZ[q00]);

        float ax = a0.x + a1.x + a2.x + b0.x + b1.x + b2.x;
        float ay = a0.y + a1.y + a2.y + b0.y + b1.y + b2.y;
        float az = zA.x + zB.x + zC.x + zB.y + zD.y + zC.y;

        float d  = fmaxf(ax * ax + ay * ay + az * az, 1e-24f);
        float rs = fast_rsqrt(d) * sg;
        int gi = (fbn + (tr + r) * NSZ + (tq + q)) * 3;
        out2[gi + 0] = ax * rs;
        out2[gi + 1] = ay * rs;
        out2[gi + 2] = az * rs;
    }
}

extern "C" void kernel_launch(void* const* d_in, const int* in_sizes, int n_in,
                              void* d_out, int out_size, void* d_ws, size_t ws_size,
                              hipStream_t stream) {
    const float* vrt = (const float*)d_in[0];
    const float* nrm = (const float*)d_in[1];
    const float* ps  = (const float*)d_in[2];

    float* out0 = (float*)d_out;                 // vert:    6*512*512*3
    float* out1 = out0 + (size_t)NPIX * 3;       // faces:   NFACE*3
    float* out2 = out1 + (size_t)F3TOT;          // normals: 6*512*512*3

    k_all<<<GRID, 256, 0, stream>>>(vrt, nrm, ps, out0, out1, out2);
}